// Round 2
// baseline (1307.384 us; speedup 1.0000x reference)
//
#include <hip/hip_runtime.h>
#include <hip/hip_bf16.h>
#include <math.h>

// Problem constants
#define BB      65536
#define LL      64
#define NSPLIT  32
#define NWID    256
#define NLAYERS 8
#define ALPHA_C 0.6f
#define TB      64      // batch rows per block

typedef float f4 __attribute__((ext_vector_type(4)));
typedef float f2 __attribute__((ext_vector_type(2)));

// Fully fused flow kernel: each block owns TB rows for the entire 8-layer chain.
// LDS: z tile 64x64 f32 (16KB) + h tile 64x256 f32 (64KB) = 80KB -> 2 blocks/CU.
// Thread (rg=tid>>5, cg=tid&31) computes an 8-row x 8-col register tile of each GEMM.
__global__ __launch_bounds__(256, 2)
void flow_fused_kernel(const float* __restrict__ x,
                       const float* __restrict__ logdet_in,
                       const float* __restrict__ bP,
                       const float* __restrict__ logsP,
                       const float* __restrict__ W1P,
                       const float* __restrict__ b1P,
                       const float* __restrict__ W2P,
                       const float* __restrict__ b2P,
                       const float* __restrict__ WfP,
                       const float* __restrict__ bfP,
                       const float* __restrict__ lgP,
                       float* __restrict__ out)
{
    __shared__ float zb[TB * LL];    // 16 KB, stride 64
    __shared__ float hb[TB * NWID];  // 64 KB, stride 256

    const int tid  = threadIdx.x;
    const int rg   = tid >> 5;   // 0..7  (row group: rows rg*8 .. rg*8+7)
    const int cg   = tid & 31;   // 0..31 (col group)
    const int row0 = blockIdx.x * TB;

    // ---- load z tile (coalesced float4) ----
    {
        const f4* xs = (const f4*)(x + (size_t)row0 * LL);
        f4* zs = (f4*)zb;
        #pragma unroll
        for (int t = 0; t < 4; ++t)
            zs[tid + t*256] = xs[tid + t*256];
    }

    float ldp[8];   // per-thread logdet partials: row rg*8+jr, this thread's cg slice
    #pragma unroll
    for (int jr = 0; jr < 8; ++jr) ldp[jr] = 0.0f;

    __syncthreads();

    #pragma unroll 1   // keep the 8-layer body un-unrolled: ~1.5K instrs, I$ is 32KB
    for (int i = 0; i < NLAYERS; ++i) {
        const float* bi  = bP    + i*LL;
        const float* li  = logsP + i*LL;
        const float* W1i = W1P   + i*NSPLIT*NWID;
        const float* b1i = b1P   + i*NWID;
        const float* W2i = W2P   + i*NWID*NWID;
        const float* b2i = b2P   + i*NWID;
        const float* Wfi = WfP   + i*NWID*64;
        const float* bfi = bfP   + i*64;

        // ---- per-column affine: z = (z + b) * exp(logs) ----
        #pragma unroll
        for (int t = 0; t < 16; ++t) {
            int idx = tid + t*256;
            int c = idx & 63;
            zb[idx] = (zb[idx] + bi[c]) * __expf(li[c]);
        }
        __syncthreads();

        // ---- GEMM1: h1 = relu(z1 @ W1 + b1)   (64x32)@(32x256) ----
        float acc[8][8];
        #pragma unroll
        for (int a = 0; a < 8; ++a)
            #pragma unroll
            for (int q = 0; q < 8; ++q) acc[a][q] = 0.0f;

        #pragma unroll 2
        for (int k0 = 0; k0 < NSPLIT; k0 += 4) {
            f4 av[8];
            #pragma unroll
            for (int jr = 0; jr < 8; ++jr)
                av[jr] = *(const f4*)&zb[(rg*8 + jr)*LL + k0];
            #pragma unroll
            for (int kk = 0; kk < 4; ++kk) {
                f4 w0 = *(const f4*)&W1i[(k0+kk)*NWID + cg*8];
                f4 w1 = *(const f4*)&W1i[(k0+kk)*NWID + cg*8 + 4];
                #pragma unroll
                for (int jr = 0; jr < 8; ++jr) {
                    float aval = av[jr][kk];
                    #pragma unroll
                    for (int j = 0; j < 4; ++j) {
                        acc[jr][j]   = fmaf(aval, w0[j], acc[jr][j]);
                        acc[jr][j+4] = fmaf(aval, w1[j], acc[jr][j+4]);
                    }
                }
            }
        }
        {   // bias + relu -> hb
            f4 q0 = *(const f4*)&b1i[cg*8];
            f4 q1 = *(const f4*)&b1i[cg*8 + 4];
            #pragma unroll
            for (int jr = 0; jr < 8; ++jr) {
                f4 r0, r1;
                #pragma unroll
                for (int j = 0; j < 4; ++j) {
                    r0[j] = fmaxf(acc[jr][j]   + q0[j], 0.0f);
                    r1[j] = fmaxf(acc[jr][j+4] + q1[j], 0.0f);
                }
                *(f4*)&hb[(rg*8 + jr)*NWID + cg*8]     = r0;
                *(f4*)&hb[(rg*8 + jr)*NWID + cg*8 + 4] = r1;
            }
        }
        __syncthreads();

        // ---- GEMM2: h2 = relu(h1 @ W2 + b2)   (64x256)@(256x256) ----
        #pragma unroll
        for (int a = 0; a < 8; ++a)
            #pragma unroll
            for (int q = 0; q < 8; ++q) acc[a][q] = 0.0f;

        #pragma unroll 2
        for (int k0 = 0; k0 < NWID; k0 += 4) {
            f4 av[8];
            #pragma unroll
            for (int jr = 0; jr < 8; ++jr)
                av[jr] = *(const f4*)&hb[(rg*8 + jr)*NWID + k0];
            #pragma unroll
            for (int kk = 0; kk < 4; ++kk) {
                f4 w0 = *(const f4*)&W2i[(k0+kk)*NWID + cg*8];
                f4 w1 = *(const f4*)&W2i[(k0+kk)*NWID + cg*8 + 4];
                #pragma unroll
                for (int jr = 0; jr < 8; ++jr) {
                    float aval = av[jr][kk];
                    #pragma unroll
                    for (int j = 0; j < 4; ++j) {
                        acc[jr][j]   = fmaf(aval, w0[j], acc[jr][j]);
                        acc[jr][j+4] = fmaf(aval, w1[j], acc[jr][j+4]);
                    }
                }
            }
        }
        __syncthreads();   // all h1 reads done before overwrite
        {   // bias + relu -> hb
            f4 q0 = *(const f4*)&b2i[cg*8];
            f4 q1 = *(const f4*)&b2i[cg*8 + 4];
            #pragma unroll
            for (int jr = 0; jr < 8; ++jr) {
                f4 r0, r1;
                #pragma unroll
                for (int j = 0; j < 4; ++j) {
                    r0[j] = fmaxf(acc[jr][j]   + q0[j], 0.0f);
                    r1[j] = fmaxf(acc[jr][j+4] + q1[j], 0.0f);
                }
                *(f4*)&hb[(rg*8 + jr)*NWID + cg*8]     = r0;
                *(f4*)&hb[(rg*8 + jr)*NWID + cg*8 + 4] = r1;
            }
        }
        __syncthreads();

        // ---- GEMM3: h3 = h2 @ Wf + bf   (64x256)@(256x64) ----
        // thread's cols = {2*cg, 2*cg+1} -> exactly the (shift,scale) pair for z2 col cg
        float acc3[8][2];
        #pragma unroll
        for (int jr = 0; jr < 8; ++jr) { acc3[jr][0] = 0.0f; acc3[jr][1] = 0.0f; }

        #pragma unroll 2
        for (int k0 = 0; k0 < NWID; k0 += 4) {
            f4 av[8];
            #pragma unroll
            for (int jr = 0; jr < 8; ++jr)
                av[jr] = *(const f4*)&hb[(rg*8 + jr)*NWID + k0];
            #pragma unroll
            for (int kk = 0; kk < 4; ++kk) {
                f2 w = *(const f2*)&Wfi[(k0+kk)*64 + cg*2];
                #pragma unroll
                for (int jr = 0; jr < 8; ++jr) {
                    float aval = av[jr][kk];
                    acc3[jr][0] = fmaf(aval, w[0], acc3[jr][0]);
                    acc3[jr][1] = fmaf(aval, w[1], acc3[jr][1]);
                }
            }
        }

        // ---- epilogue: gated update of z2, logdet partials ----
        {
            float bsh = bfi[2*cg];
            float bsc = bfi[2*cg + 1];
            float eg  = __expf(lgP[i*32 + cg]);
            #pragma unroll
            for (int jr = 0; jr < 8; ++jr) {
                int r = rg*8 + jr;
                float sh = eg * tanhf(acc3[jr][0] + bsh);
                float sc = ALPHA_C * tanhf(acc3[jr][1] + bsc);
                float zv = zb[r*LL + NSPLIT + cg];
                zb[r*LL + NSPLIT + cg] = fmaf(sc, zv, zv + sh);
                ldp[jr] += log1pf(sc);
            }
        }
        __syncthreads();

        // ---- reversal: z = z[:, ::-1] (in-place pair swap) ----
        #pragma unroll
        for (int t = 0; t < 8; ++t) {
            int idx = tid + t*256;
            int r = idx >> 5;
            int c = idx & 31;
            float aL = zb[r*LL + c];
            float aR = zb[r*LL + 63 - c];
            zb[r*LL + c]      = aR;
            zb[r*LL + 63 - c] = aL;
        }
        __syncthreads();
    }

    // ---- store z ----
    {
        f4* oz = (f4*)(out + (size_t)row0 * LL);
        const f4* zs = (const f4*)zb;
        #pragma unroll
        for (int t = 0; t < 4; ++t)
            oz[tid + t*256] = zs[tid + t*256];
    }

    // ---- logdet: sum over all layers of sum(logs[i]) is a single scalar ----
    float lsum = 0.0f;
    if (cg == 0) {
        float s0 = 0.f, s1 = 0.f, s2 = 0.f, s3 = 0.f;
        #pragma unroll 4
        for (int p = 0; p < NLAYERS*LL; p += 4) {
            s0 += logsP[p];   s1 += logsP[p+1];
            s2 += logsP[p+2]; s3 += logsP[p+3];
        }
        lsum = (s0 + s1) + (s2 + s3);
    }
    // reduce ldp over the 32 cg lanes (half-wave) and write one value per row
    #pragma unroll
    for (int jr = 0; jr < 8; ++jr) {
        float v = ldp[jr];
        v += __shfl_xor(v, 16);
        v += __shfl_xor(v, 8);
        v += __shfl_xor(v, 4);
        v += __shfl_xor(v, 2);
        v += __shfl_xor(v, 1);
        if (cg == 0) {
            int r = row0 + rg*8 + jr;
            out[(size_t)BB*LL + r] = logdet_in[r] + lsum + v;
        }
    }
}

extern "C" void kernel_launch(void* const* d_in, const int* in_sizes, int n_in,
                              void* d_out, int out_size, void* d_ws, size_t ws_size,
                              hipStream_t stream)
{
    const float* x    = (const float*)d_in[0];
    const float* ld   = (const float*)d_in[1];
    const float* b    = (const float*)d_in[2];
    const float* logs = (const float*)d_in[3];
    const float* W1   = (const float*)d_in[4];
    const float* b1   = (const float*)d_in[5];
    const float* W2   = (const float*)d_in[6];
    const float* b2   = (const float*)d_in[7];
    const float* Wf   = (const float*)d_in[8];
    const float* bf_  = (const float*)d_in[9];
    const float* lgm  = (const float*)d_in[10];
    float* out = (float*)d_out;

    dim3 grid(BB / TB);   // 1024 blocks, 64 rows each
    dim3 block(256);
    hipLaunchKernelGGL(flow_fused_kernel, grid, block, 0, stream,
                       x, ld, b, logs, W1, b1, W2, b2, Wf, bf_, lgm, out);
}

// Round 5
// 733.385 us; speedup vs baseline: 1.7827x; 1.7827x over previous
//
#include <hip/hip_runtime.h>
#include <math.h>

#define BB 65536
#define ND 8

typedef float f4 __attribute__((ext_vector_type(4)));
typedef float f32x4 __attribute__((ext_vector_type(4)));
typedef _Float16 half8 __attribute__((ext_vector_type(8)));
typedef __fp16 fp16x2 __attribute__((ext_vector_type(2)));   // return type of cvt_pkrtz

// d_ws layout (f16 elements): [hi: W1t|W2t|Wft][lo: W1t|W2t|Wft]
// W1t [8][256][32], W2t [8][256][256], Wft [8][64][256]  (all n-major, k-contiguous)
#define W1T_OFF 0
#define W2T_OFF 65536
#define WFT_OFF (65536 + 524288)
#define WTOT    720896

#define MFMA16(a, b, c) __builtin_amdgcn_mfma_f32_16x16x32_f16((a), (b), (c), 0, 0, 0)

// ---------- weight transpose + hi/lo split (runs every launch; ~3 MB traffic) ----------
__global__ __launch_bounds__(256)
void prep_weights(const float* __restrict__ W1, const float* __restrict__ W2,
                  const float* __restrict__ Wf, _Float16* __restrict__ wt)
{
    int t = blockIdx.x * 256 + threadIdx.x;
    if (t < 65536) {                    // W1t [i][n256][k32] <- W1 [i][k32][n256]
        int i = t >> 13, rem = t & 8191;
        int n = rem >> 5, k = rem & 31;
        float wv = W1[i*8192 + k*256 + n];
        _Float16 hi = (_Float16)wv;
        wt[W1T_OFF + t]        = hi;
        wt[WTOT + W1T_OFF + t] = (_Float16)(wv - (float)hi);
    }
    if (t < 524288) {                   // W2t [i][n256][k256] <- W2 [i][k256][n256]
        int i = t >> 16, rem = t & 65535;
        int n = rem >> 8, k = rem & 255;
        float wv = W2[i*65536 + k*256 + n];
        _Float16 hi = (_Float16)wv;
        wt[W2T_OFF + t]        = hi;
        wt[WTOT + W2T_OFF + t] = (_Float16)(wv - (float)hi);
    }
    if (t < 131072) {                   // Wft [i][n64][k256] <- Wf [i][k256][n64]
        int i = t >> 14, rem = t & 16383;
        int n = rem >> 8, k = rem & 255;
        float wv = Wf[i*16384 + k*64 + n];
        _Float16 hi = (_Float16)wv;
        wt[WFT_OFF + t]        = hi;
        wt[WTOT + WFT_OFF + t] = (_Float16)(wv - (float)hi);
    }
}

// split 8 fp32 -> f16 hi + f16 lo fragments (k-ascending).
// cvt_pkrtz returns fp16x2 (__fp16); union-pun to half8 (_Float16) — same binary16 bits.
__device__ __forceinline__ void split8(f4 a, f4 b, half8& hi, half8& lo)
{
    union U { half8 v; fp16x2 h[4]; } H, L;
    H.h[0] = __builtin_amdgcn_cvt_pkrtz(a[0], a[1]);
    H.h[1] = __builtin_amdgcn_cvt_pkrtz(a[2], a[3]);
    H.h[2] = __builtin_amdgcn_cvt_pkrtz(b[0], b[1]);
    H.h[3] = __builtin_amdgcn_cvt_pkrtz(b[2], b[3]);
    L.h[0] = __builtin_amdgcn_cvt_pkrtz(a[0] - (float)H.h[0][0], a[1] - (float)H.h[0][1]);
    L.h[1] = __builtin_amdgcn_cvt_pkrtz(a[2] - (float)H.h[1][0], a[3] - (float)H.h[1][1]);
    L.h[2] = __builtin_amdgcn_cvt_pkrtz(b[0] - (float)H.h[2][0], b[1] - (float)H.h[2][1]);
    L.h[3] = __builtin_amdgcn_cvt_pkrtz(b[2] - (float)H.h[3][0], b[3] - (float)H.h[3][1]);
    hi = H.v; lo = L.v;
}

// Fused 8-layer flow. 64 rows/block, 4 waves as 2(row-half) x 2(n-half).
// zb: fp32 [64][64], hb: fp32 [64][256]; both XOR-swizzled per f4 block:
//   elem (r,c) at  r*W + ((c>>2) ^ (r&7))*4 + (c&3)
// MFMA orientation: A = weight rows (n-major, k-contig, global), B = activation rows
// (k-contig, LDS) -> D[n][batchrow]; lane holds 4 consecutive n for one row.
__global__ __launch_bounds__(256, 2)
void flow_mfma(const float* __restrict__ x,
               const float* __restrict__ logdet_in,
               const float* __restrict__ bP,
               const float* __restrict__ logsP,
               const float* __restrict__ b1P,
               const float* __restrict__ b2P,
               const float* __restrict__ bfP,
               const float* __restrict__ lgP,
               const _Float16* __restrict__ wt,
               float* __restrict__ out)
{
    __shared__ float zb[64 * 64];    // 16 KB
    __shared__ float hb[64 * 256];   // 64 KB  (reused as logdet scratch at end)

    const int tid  = threadIdx.x;
    const int w    = tid >> 6;
    const int wr   = w >> 1;          // row half
    const int wc   = w & 1;           // n half
    const int lane = tid & 63;
    const int li   = lane & 15;
    const int lg4  = lane >> 4;
    const int row0 = blockIdx.x * 64;

    // scalar sum of ALL logs (same for every row) -- per-thread, no LDS
    float lsum;
    {
        float s = 0.f;
        #pragma unroll
        for (int i2 = 0; i2 < 8; ++i2) s += logsP[i2*64 + lane];
        s += __shfl_xor(s, 1);  s += __shfl_xor(s, 2);  s += __shfl_xor(s, 4);
        s += __shfl_xor(s, 8);  s += __shfl_xor(s, 16); s += __shfl_xor(s, 32);
        lsum = s;
    }

    // load z tile (swizzled)
    {
        const f4* xs = (const f4*)(x + (size_t)row0 * 64);
        #pragma unroll
        for (int q = 0; q < 4; ++q) {
            int idx4 = tid + q*256;
            int r = idx4 >> 4, cf = idx4 & 15;
            *(f4*)&zb[r*64 + ((cf ^ (r & 7)) << 2)] = xs[idx4];
        }
    }

    const int rA = (wr*2 + 0)*16 + li;   // this lane's two batch rows
    const int rB = (wr*2 + 1)*16 + li;
    const int sA = rA & 7, sB = rB & 7;

    float ldp0 = 0.f, ldp1 = 0.f;
    const f32x4 zero4 = {0.f, 0.f, 0.f, 0.f};

    #pragma unroll 1   // body is ~1.5K instrs with ~500 MFMAs; 8x unroll would blow I$
    for (int i = 0; i < ND; ++i) {
        __syncthreads();   // covers z-load (iter 0) and reversal (iters >0)

        // ---- affine: z = (z + b) * exp(logs) ----
        #pragma unroll
        for (int q = 0; q < 4; ++q) {
            int idx4 = tid + q*256;
            int r = idx4 >> 4, cf = idx4 & 15;
            float* zp = &zb[r*64 + ((cf ^ (r & 7)) << 2)];
            f4 z  = *(f4*)zp;
            f4 bv = *(const f4*)&bP[i*64 + cf*4];
            f4 lv = *(const f4*)&logsP[i*64 + cf*4];
            f4 ev = { __expf(lv[0]), __expf(lv[1]), __expf(lv[2]), __expf(lv[3]) };
            z = (z + bv) * ev;
            *(f4*)zp = z;
        }
        __syncthreads();

        // ---- GEMM1: h1 = relu(z1 @ W1 + b1)  (K=32, one k-step) ----
        {
            half8 bh0, bl0, bh1, bl1;
            {
                int cf = lg4 * 2;
                f4 a0 = *(const f4*)&zb[rA*64 + (((cf    ) ^ sA) << 2)];
                f4 a1 = *(const f4*)&zb[rA*64 + (((cf + 1) ^ sA) << 2)];
                split8(a0, a1, bh0, bl0);
                f4 c0 = *(const f4*)&zb[rB*64 + (((cf    ) ^ sB) << 2)];
                f4 c1 = *(const f4*)&zb[rB*64 + (((cf + 1) ^ sB) << 2)];
                split8(c0, c1, bh1, bl1);
            }
            f32x4 acc[8][2];
            #pragma unroll
            for (int nt = 0; nt < 8; ++nt) { acc[nt][0] = zero4; acc[nt][1] = zero4; }
            const _Float16* w1h = wt + W1T_OFF + i*8192;
            const _Float16* w1l = w1h + WTOT;
            #pragma unroll
            for (int nt = 0; nt < 8; ++nt) {
                int n = wc*128 + nt*16 + li;
                half8 ah = *(const half8*)&w1h[n*32 + lg4*8];
                half8 al = *(const half8*)&w1l[n*32 + lg4*8];
                acc[nt][0] = MFMA16(ah, bh0, acc[nt][0]);
                acc[nt][1] = MFMA16(ah, bh1, acc[nt][1]);
                acc[nt][0] = MFMA16(ah, bl0, acc[nt][0]);
                acc[nt][1] = MFMA16(ah, bl1, acc[nt][1]);
                acc[nt][0] = MFMA16(al, bh0, acc[nt][0]);
                acc[nt][1] = MFMA16(al, bh1, acc[nt][1]);
            }
            const float* bb = b1P + i*256;
            #pragma unroll
            for (int nt = 0; nt < 8; ++nt) {
                int n0 = wc*128 + nt*16 + lg4*4;
                f4 bias = *(const f4*)&bb[n0];
                int cfw = n0 >> 2;
                #pragma unroll
                for (int rt = 0; rt < 2; ++rt) {
                    int r  = rt ? rB : rA;
                    int sr = rt ? sB : sA;
                    f4 v = acc[nt][rt] + bias;
                    v[0] = fmaxf(v[0], 0.f); v[1] = fmaxf(v[1], 0.f);
                    v[2] = fmaxf(v[2], 0.f); v[3] = fmaxf(v[3], 0.f);
                    *(f4*)&hb[r*256 + ((cfw ^ sr) << 2)] = v;
                }
            }
        }
        __syncthreads();

        // ---- GEMM2: h2 = relu(h1 @ W2 + b2)  (K=256) ----
        {
            f32x4 acc[8][2];
            #pragma unroll
            for (int nt = 0; nt < 8; ++nt) { acc[nt][0] = zero4; acc[nt][1] = zero4; }
            const _Float16* w2h = wt + W2T_OFF + i*65536;
            const _Float16* w2l = w2h + WTOT;
            #pragma unroll 2
            for (int ks = 0; ks < 8; ++ks) {
                int cf = ks*8 + lg4*2;
                half8 ph0, pl0, ph1, pl1;
                f4 a0 = *(const f4*)&hb[rA*256 + (((cf    ) ^ sA) << 2)];
                f4 a1 = *(const f4*)&hb[rA*256 + (((cf + 1) ^ sA) << 2)];
                split8(a0, a1, ph0, pl0);
                f4 c0 = *(const f4*)&hb[rB*256 + (((cf    ) ^ sB) << 2)];
                f4 c1 = *(const f4*)&hb[rB*256 + (((cf + 1) ^ sB) << 2)];
                split8(c0, c1, ph1, pl1);
                int kb = ks*32 + lg4*8;
                #pragma unroll
                for (int nt = 0; nt < 8; ++nt) {
                    int n = wc*128 + nt*16 + li;
                    half8 ah = *(const half8*)&w2h[n*256 + kb];
                    half8 al = *(const half8*)&w2l[n*256 + kb];
                    acc[nt][0] = MFMA16(ah, ph0, acc[nt][0]);
                    acc[nt][1] = MFMA16(ah, ph1, acc[nt][1]);
                    acc[nt][0] = MFMA16(ah, pl0, acc[nt][0]);
                    acc[nt][1] = MFMA16(ah, pl1, acc[nt][1]);
                    acc[nt][0] = MFMA16(al, ph0, acc[nt][0]);
                    acc[nt][1] = MFMA16(al, ph1, acc[nt][1]);
                }
            }
            __syncthreads();   // all h1 reads done before overwrite
            const float* bb = b2P + i*256;
            #pragma unroll
            for (int nt = 0; nt < 8; ++nt) {
                int n0 = wc*128 + nt*16 + lg4*4;
                f4 bias = *(const f4*)&bb[n0];
                int cfw = n0 >> 2;
                #pragma unroll
                for (int rt = 0; rt < 2; ++rt) {
                    int r  = rt ? rB : rA;
                    int sr = rt ? sB : sA;
                    f4 v = acc[nt][rt] + bias;
                    v[0] = fmaxf(v[0], 0.f); v[1] = fmaxf(v[1], 0.f);
                    v[2] = fmaxf(v[2], 0.f); v[3] = fmaxf(v[3], 0.f);
                    *(f4*)&hb[r*256 + ((cfw ^ sr) << 2)] = v;
                }
            }
        }
        __syncthreads();

        // ---- GEMM3: h3 = h2 @ Wf + bf  -> gated z2 update + logdet ----
        {
            f32x4 acc[2][2];
            acc[0][0] = zero4; acc[0][1] = zero4; acc[1][0] = zero4; acc[1][1] = zero4;
            const _Float16* wfh = wt + WFT_OFF + i*16384;
            const _Float16* wfl = wfh + WTOT;
            #pragma unroll 2
            for (int ks = 0; ks < 8; ++ks) {
                int cf = ks*8 + lg4*2;
                half8 ph0, pl0, ph1, pl1;
                f4 a0 = *(const f4*)&hb[rA*256 + (((cf    ) ^ sA) << 2)];
                f4 a1 = *(const f4*)&hb[rA*256 + (((cf + 1) ^ sA) << 2)];
                split8(a0, a1, ph0, pl0);
                f4 c0 = *(const f4*)&hb[rB*256 + (((cf    ) ^ sB) << 2)];
                f4 c1 = *(const f4*)&hb[rB*256 + (((cf + 1) ^ sB) << 2)];
                split8(c0, c1, ph1, pl1);
                int kb = ks*32 + lg4*8;
                #pragma unroll
                for (int nt = 0; nt < 2; ++nt) {
                    int n = (wc*2 + nt)*16 + li;
                    half8 ah = *(const half8*)&wfh[n*256 + kb];
                    half8 al = *(const half8*)&wfl[n*256 + kb];
                    acc[nt][0] = MFMA16(ah, ph0, acc[nt][0]);
                    acc[nt][1] = MFMA16(ah, ph1, acc[nt][1]);
                    acc[nt][0] = MFMA16(ah, pl0, acc[nt][0]);
                    acc[nt][1] = MFMA16(ah, pl1, acc[nt][1]);
                    acc[nt][0] = MFMA16(al, ph0, acc[nt][0]);
                    acc[nt][1] = MFMA16(al, ph1, acc[nt][1]);
                }
            }
            // epilogue: lane holds (shift,scale) pairs for 2 j-values x 2 rows
            #pragma unroll
            for (int nt = 0; nt < 2; ++nt) {
                int n0 = (wc*2 + nt)*16 + lg4*4;
                int j0 = n0 >> 1;
                f4 bias = *(const f4*)&bfP[i*64 + n0];
                float eg0 = __expf(lgP[i*32 + j0]);
                float eg1 = __expf(lgP[i*32 + j0 + 1]);
                #pragma unroll
                for (int rt = 0; rt < 2; ++rt) {
                    int r  = rt ? rB : rA;
                    int sr = rt ? sB : sA;
                    f4 v = acc[nt][rt];
                    float sh0 = eg0  * tanhf(v[0] + bias[0]);
                    float sc0 = 0.6f * tanhf(v[1] + bias[1]);
                    float sh1 = eg1  * tanhf(v[2] + bias[2]);
                    float sc1 = 0.6f * tanhf(v[3] + bias[3]);
                    int c = 32 + j0;                       // j0, j0+1 share an f4 block
                    int addr = r*64 + ((((c >> 2) ^ sr)) << 2) + (c & 3);
                    float z0  = zb[addr];
                    float z1v = zb[addr + 1];
                    zb[addr]     = fmaf(sc0, z0,  z0  + sh0);
                    zb[addr + 1] = fmaf(sc1, z1v, z1v + sh1);
                    float l01 = log1pf(sc0) + log1pf(sc1);
                    if (rt == 0) ldp0 += l01; else ldp1 += l01;
                }
            }
        }
        __syncthreads();

        // ---- reversal: z = z[:, ::-1] (logical f4-block pair swap) ----
        #pragma unroll
        for (int q = 0; q < 2; ++q) {
            int task = tid + q*256;          // 512 tasks = 64 rows x 8 left blocks
            int r = task >> 3, cfL = task & 7;
            int s = r & 7;
            float* pL = &zb[r*64 + ((cfL ^ s) << 2)];
            float* pR = &zb[r*64 + (((15 - cfL) ^ s) << 2)];
            f4 Lv = *(f4*)pL;
            f4 Rv = *(f4*)pR;
            f4 nL = { Rv[3], Rv[2], Rv[1], Rv[0] };
            f4 nR = { Lv[3], Lv[2], Lv[1], Lv[0] };
            *(f4*)pL = nL;
            *(f4*)pR = nR;
        }
    }
    __syncthreads();

    // ---- store z ----
    {
        f4* oz = (f4*)(out + (size_t)row0 * 64);
        #pragma unroll
        for (int q = 0; q < 4; ++q) {
            int idx4 = tid + q*256;
            int r = idx4 >> 4, cf = idx4 & 15;
            oz[idx4] = *(const f4*)&zb[r*64 + ((cf ^ (r & 7)) << 2)];
        }
    }

    // ---- logdet: reduce ldp over the 4 lane-groups, combine wc halves via hb scratch ----
    float v0 = ldp0 + __shfl_xor(ldp0, 16); v0 += __shfl_xor(v0, 32);
    float v1 = ldp1 + __shfl_xor(ldp1, 16); v1 += __shfl_xor(v1, 32);
    if (lg4 == 0) {
        hb[rA*2 + wc] = v0;
        hb[rB*2 + wc] = v1;
    }
    __syncthreads();
    if (tid < 64) {
        int gr = row0 + tid;
        out[(size_t)BB * 64 + gr] = logdet_in[gr] + lsum + hb[tid*2] + hb[tid*2 + 1];
    }
}

extern "C" void kernel_launch(void* const* d_in, const int* in_sizes, int n_in,
                              void* d_out, int out_size, void* d_ws, size_t ws_size,
                              hipStream_t stream)
{
    const float* x    = (const float*)d_in[0];
    const float* ld   = (const float*)d_in[1];
    const float* b    = (const float*)d_in[2];
    const float* logs = (const float*)d_in[3];
    const float* W1   = (const float*)d_in[4];
    const float* b1   = (const float*)d_in[5];
    const float* W2   = (const float*)d_in[6];
    const float* b2   = (const float*)d_in[7];
    const float* Wf   = (const float*)d_in[8];
    const float* bf   = (const float*)d_in[9];
    const float* lg   = (const float*)d_in[10];
    _Float16* wt = (_Float16*)d_ws;
    float* out = (float*)d_out;

    prep_weights<<<2048, 256, 0, stream>>>(W1, W2, Wf, wt);
    flow_mfma<<<1024, 256, 0, stream>>>(x, ld, b, logs, b1, b2, bf, lg, wt, out);
}

// Round 6
// 433.297 us; speedup vs baseline: 3.0173x; 1.6926x over previous
//
#include <hip/hip_runtime.h>
#include <math.h>

#define BB 65536
#define ND 8

typedef float f4 __attribute__((ext_vector_type(4)));
typedef float f32x4 __attribute__((ext_vector_type(4)));
typedef _Float16 half8 __attribute__((ext_vector_type(8)));
typedef __fp16 fp16x2 __attribute__((ext_vector_type(2)));   // return type of cvt_pkrtz

// d_ws: weights in MFMA-FRAGMENT ORDER. One record = 512 f16 (1 KiB): lane l's
// 8 f16 at record + l*8. Record pairs: [hi][lo] adjacent (stride 512 f16).
//   F1: rec = (i*16 + nt)*2 + p            nt=0..15  -> n=nt*16+li, k=lg4*8+j
//   F2: rec = ((i*8+ks)*16 + nt)*2 + p     ks=0..7   -> k=ks*32+lg4*8+j
//   F3: rec = ((i*8+ks)*4  + nt)*2 + p     nt=0..3 (n<64)
#define F1_OFF 0
#define F2_OFF 131072
#define F3_OFF 1179648
#define WTOT_F16 1441792   // = 2,883,584 bytes, same ws footprint as before

#define MFMA16(a, b, c) __builtin_amdgcn_mfma_f32_16x16x32_f16((a), (b), (c), 0, 0, 0)

// ---------- weight transpose + hi/lo split into fragment order ----------
__global__ __launch_bounds__(256)
void prep_weights(const float* __restrict__ W1, const float* __restrict__ W2,
                  const float* __restrict__ Wf, _Float16* __restrict__ wt)
{
    int t = blockIdx.x * 256 + threadIdx.x;   // dest f16 index; grid covers exactly WTOT_F16
    float wv;
    int p;
    if (t < F2_OFF) {                         // W1 frags
        int rec = t >> 9, off = t & 511;
        p = rec & 1;
        int nt = (rec >> 1) & 15, i = rec >> 5;
        int l = off >> 3, j = off & 7;
        int n = nt*16 + (l & 15), k = (l >> 4)*8 + j;
        wv = W1[i*8192 + k*256 + n];
    } else if (t < F3_OFF) {                  // W2 frags
        int u = t - F2_OFF;
        int rec = u >> 9, off = u & 511;
        p = rec & 1;
        int nt = (rec >> 1) & 15, ks = (rec >> 5) & 7, i = rec >> 8;
        int l = off >> 3, j = off & 7;
        int n = nt*16 + (l & 15), k = ks*32 + (l >> 4)*8 + j;
        wv = W2[i*65536 + k*256 + n];
    } else {                                  // Wf frags
        int u = t - F3_OFF;
        int rec = u >> 9, off = u & 511;
        p = rec & 1;
        int nt = (rec >> 1) & 3, ks = (rec >> 3) & 7, i = rec >> 6;
        int l = off >> 3, j = off & 7;
        int n = nt*16 + (l & 15), k = ks*32 + (l >> 4)*8 + j;
        wv = Wf[i*16384 + k*64 + n];
    }
    _Float16 hi = (_Float16)wv;
    wt[t] = p ? (_Float16)(wv - (float)hi) : hi;
}

// split 8 fp32 -> f16 hi + f16 lo fragments (k-ascending).
__device__ __forceinline__ void split8(f4 a, f4 b, half8& hi, half8& lo)
{
    union U { half8 v; fp16x2 h[4]; } H, L;
    H.h[0] = __builtin_amdgcn_cvt_pkrtz(a[0], a[1]);
    H.h[1] = __builtin_amdgcn_cvt_pkrtz(a[2], a[3]);
    H.h[2] = __builtin_amdgcn_cvt_pkrtz(b[0], b[1]);
    H.h[3] = __builtin_amdgcn_cvt_pkrtz(b[2], b[3]);
    L.h[0] = __builtin_amdgcn_cvt_pkrtz(a[0] - (float)H.h[0][0], a[1] - (float)H.h[0][1]);
    L.h[1] = __builtin_amdgcn_cvt_pkrtz(a[2] - (float)H.h[1][0], a[3] - (float)H.h[1][1]);
    L.h[2] = __builtin_amdgcn_cvt_pkrtz(b[0] - (float)H.h[2][0], b[1] - (float)H.h[2][1]);
    L.h[3] = __builtin_amdgcn_cvt_pkrtz(b[2] - (float)H.h[3][0], b[3] - (float)H.h[3][1]);
    hi = H.v; lo = L.v;
}

// Fused 8-layer flow. 64 rows/block, 4 waves as 2(row-half) x 2(n-half).
// zb: fp32 [64][64], hb: fp32 [64][256]; both XOR-swizzled per f4 block:
//   elem (r,c) at  r*W + ((c>>2) ^ (r&7))*4 + (c&3)
// MFMA: A = weight frag (global, fragment-ordered, coalesced), B = activation rows
// (k-contig, LDS) -> D[n][batchrow]; lane holds 4 consecutive n for one row.
__global__ __launch_bounds__(256, 2)
void flow_mfma(const float* __restrict__ x,
               const float* __restrict__ logdet_in,
               const float* __restrict__ bP,
               const float* __restrict__ logsP,
               const float* __restrict__ b1P,
               const float* __restrict__ b2P,
               const float* __restrict__ bfP,
               const float* __restrict__ lgP,
               const _Float16* __restrict__ wt,
               float* __restrict__ out)
{
    __shared__ float zb[64 * 64];    // 16 KB
    __shared__ float hb[64 * 256];   // 64 KB  (reused as logdet scratch at end)

    const int tid  = threadIdx.x;
    const int w    = tid >> 6;
    const int wr   = w >> 1;          // row half
    const int wc   = w & 1;           // n half
    const int lane = tid & 63;
    const int li   = lane & 15;
    const int lg4  = lane >> 4;
    const int row0 = blockIdx.x * 64;

    // scalar sum of ALL logs (same for every row) -- per-thread, no LDS
    float lsum;
    {
        float s = 0.f;
        #pragma unroll
        for (int i2 = 0; i2 < 8; ++i2) s += logsP[i2*64 + lane];
        s += __shfl_xor(s, 1);  s += __shfl_xor(s, 2);  s += __shfl_xor(s, 4);
        s += __shfl_xor(s, 8);  s += __shfl_xor(s, 16); s += __shfl_xor(s, 32);
        lsum = s;
    }

    // load z tile (swizzled)
    {
        const f4* xs = (const f4*)(x + (size_t)row0 * 64);
        #pragma unroll
        for (int q = 0; q < 4; ++q) {
            int idx4 = tid + q*256;
            int r = idx4 >> 4, cf = idx4 & 15;
            *(f4*)&zb[r*64 + ((cf ^ (r & 7)) << 2)] = xs[idx4];
        }
    }

    const int rA = (wr*2 + 0)*16 + li;   // this lane's two batch rows
    const int rB = (wr*2 + 1)*16 + li;
    const int sA = rA & 7, sB = rB & 7;

    float ldp0 = 0.f, ldp1 = 0.f;
    const f32x4 zero4 = {0.f, 0.f, 0.f, 0.f};

    #pragma unroll 1   // body is ~1.5K instrs with ~500 MFMAs; 8x unroll would blow I$
    for (int i = 0; i < ND; ++i) {
        __syncthreads();   // covers z-load (iter 0) and reversal (iters >0)

        // ---- affine: z = (z + b) * exp(logs) ----
        #pragma unroll
        for (int q = 0; q < 4; ++q) {
            int idx4 = tid + q*256;
            int r = idx4 >> 4, cf = idx4 & 15;
            float* zp = &zb[r*64 + ((cf ^ (r & 7)) << 2)];
            f4 z  = *(f4*)zp;
            f4 bv = *(const f4*)&bP[i*64 + cf*4];
            f4 lv = *(const f4*)&logsP[i*64 + cf*4];
            f4 ev = { __expf(lv[0]), __expf(lv[1]), __expf(lv[2]), __expf(lv[3]) };
            z = (z + bv) * ev;
            *(f4*)zp = z;
        }
        __syncthreads();

        // ---- GEMM1: h1 = relu(z1 @ W1 + b1)  (K=32, one k-step) ----
        {
            half8 bh0, bl0, bh1, bl1;
            {
                int cf = lg4 * 2;
                f4 a0 = *(const f4*)&zb[rA*64 + (((cf    ) ^ sA) << 2)];
                f4 a1 = *(const f4*)&zb[rA*64 + (((cf + 1) ^ sA) << 2)];
                split8(a0, a1, bh0, bl0);
                f4 c0 = *(const f4*)&zb[rB*64 + (((cf    ) ^ sB) << 2)];
                f4 c1 = *(const f4*)&zb[rB*64 + (((cf + 1) ^ sB) << 2)];
                split8(c0, c1, bh1, bl1);
            }
            f32x4 acc[8][2];
            #pragma unroll
            for (int nt = 0; nt < 8; ++nt) { acc[nt][0] = zero4; acc[nt][1] = zero4; }
            const _Float16* w1f = wt + F1_OFF + i*16384 + lane*8;
            #pragma unroll
            for (int nt = 0; nt < 8; ++nt) {
                const _Float16* fb = w1f + (wc*8 + nt)*1024;
                half8 ah = *(const half8*)fb;
                half8 al = *(const half8*)(fb + 512);
                acc[nt][0] = MFMA16(ah, bh0, acc[nt][0]);
                acc[nt][1] = MFMA16(ah, bh1, acc[nt][1]);
                acc[nt][0] = MFMA16(ah, bl0, acc[nt][0]);
                acc[nt][1] = MFMA16(ah, bl1, acc[nt][1]);
                acc[nt][0] = MFMA16(al, bh0, acc[nt][0]);
                acc[nt][1] = MFMA16(al, bh1, acc[nt][1]);
            }
            const float* bb = b1P + i*256;
            #pragma unroll
            for (int nt = 0; nt < 8; ++nt) {
                int n0 = wc*128 + nt*16 + lg4*4;
                f4 bias = *(const f4*)&bb[n0];
                int cfw = n0 >> 2;
                #pragma unroll
                for (int rt = 0; rt < 2; ++rt) {
                    int r  = rt ? rB : rA;
                    int sr = rt ? sB : sA;
                    f4 v = acc[nt][rt] + bias;
                    v[0] = fmaxf(v[0], 0.f); v[1] = fmaxf(v[1], 0.f);
                    v[2] = fmaxf(v[2], 0.f); v[3] = fmaxf(v[3], 0.f);
                    *(f4*)&hb[r*256 + ((cfw ^ sr) << 2)] = v;
                }
            }
        }
        __syncthreads();

        // ---- GEMM2: h2 = relu(h1 @ W2 + b2)  (K=256) ----
        {
            f32x4 acc[8][2];
            #pragma unroll
            for (int nt = 0; nt < 8; ++nt) { acc[nt][0] = zero4; acc[nt][1] = zero4; }
            const _Float16* w2f = wt + F2_OFF + i*131072 + lane*8;
            #pragma unroll 2
            for (int ks = 0; ks < 8; ++ks) {
                int cf = ks*8 + lg4*2;
                half8 ph0, pl0, ph1, pl1;
                f4 a0 = *(const f4*)&hb[rA*256 + (((cf    ) ^ sA) << 2)];
                f4 a1 = *(const f4*)&hb[rA*256 + (((cf + 1) ^ sA) << 2)];
                split8(a0, a1, ph0, pl0);
                f4 c0 = *(const f4*)&hb[rB*256 + (((cf    ) ^ sB) << 2)];
                f4 c1 = *(const f4*)&hb[rB*256 + (((cf + 1) ^ sB) << 2)];
                split8(c0, c1, ph1, pl1);
                const _Float16* wk = w2f + ks*16384;
                #pragma unroll
                for (int nt = 0; nt < 8; ++nt) {
                    const _Float16* fb = wk + (wc*8 + nt)*1024;
                    half8 ah = *(const half8*)fb;
                    half8 al = *(const half8*)(fb + 512);
                    acc[nt][0] = MFMA16(ah, ph0, acc[nt][0]);
                    acc[nt][1] = MFMA16(ah, ph1, acc[nt][1]);
                    acc[nt][0] = MFMA16(ah, pl0, acc[nt][0]);
                    acc[nt][1] = MFMA16(ah, pl1, acc[nt][1]);
                    acc[nt][0] = MFMA16(al, ph0, acc[nt][0]);
                    acc[nt][1] = MFMA16(al, ph1, acc[nt][1]);
                }
            }
            __syncthreads();   // all h1 reads done before overwrite
            const float* bb = b2P + i*256;
            #pragma unroll
            for (int nt = 0; nt < 8; ++nt) {
                int n0 = wc*128 + nt*16 + lg4*4;
                f4 bias = *(const f4*)&bb[n0];
                int cfw = n0 >> 2;
                #pragma unroll
                for (int rt = 0; rt < 2; ++rt) {
                    int r  = rt ? rB : rA;
                    int sr = rt ? sB : sA;
                    f4 v = acc[nt][rt] + bias;
                    v[0] = fmaxf(v[0], 0.f); v[1] = fmaxf(v[1], 0.f);
                    v[2] = fmaxf(v[2], 0.f); v[3] = fmaxf(v[3], 0.f);
                    *(f4*)&hb[r*256 + ((cfw ^ sr) << 2)] = v;
                }
            }
        }
        __syncthreads();

        // ---- GEMM3: h3 = h2 @ Wf + bf  -> gated z2 update + logdet ----
        {
            f32x4 acc[2][2];
            acc[0][0] = zero4; acc[0][1] = zero4; acc[1][0] = zero4; acc[1][1] = zero4;
            const _Float16* w3f = wt + F3_OFF + i*32768 + lane*8;
            #pragma unroll 2
            for (int ks = 0; ks < 8; ++ks) {
                int cf = ks*8 + lg4*2;
                half8 ph0, pl0, ph1, pl1;
                f4 a0 = *(const f4*)&hb[rA*256 + (((cf    ) ^ sA) << 2)];
                f4 a1 = *(const f4*)&hb[rA*256 + (((cf + 1) ^ sA) << 2)];
                split8(a0, a1, ph0, pl0);
                f4 c0 = *(const f4*)&hb[rB*256 + (((cf    ) ^ sB) << 2)];
                f4 c1 = *(const f4*)&hb[rB*256 + (((cf + 1) ^ sB) << 2)];
                split8(c0, c1, ph1, pl1);
                const _Float16* wk = w3f + ks*4096;
                #pragma unroll
                for (int nt = 0; nt < 2; ++nt) {
                    const _Float16* fb = wk + (wc*2 + nt)*1024;
                    half8 ah = *(const half8*)fb;
                    half8 al = *(const half8*)(fb + 512);
                    acc[nt][0] = MFMA16(ah, ph0, acc[nt][0]);
                    acc[nt][1] = MFMA16(ah, ph1, acc[nt][1]);
                    acc[nt][0] = MFMA16(ah, pl0, acc[nt][0]);
                    acc[nt][1] = MFMA16(ah, pl1, acc[nt][1]);
                    acc[nt][0] = MFMA16(al, ph0, acc[nt][0]);
                    acc[nt][1] = MFMA16(al, ph1, acc[nt][1]);
                }
            }
            // epilogue: lane holds (shift,scale) pairs for 2 j-values x 2 rows
            #pragma unroll
            for (int nt = 0; nt < 2; ++nt) {
                int n0 = (wc*2 + nt)*16 + lg4*4;
                int j0 = n0 >> 1;
                f4 bias = *(const f4*)&bfP[i*64 + n0];
                float eg0 = __expf(lgP[i*32 + j0]);
                float eg1 = __expf(lgP[i*32 + j0 + 1]);
                #pragma unroll
                for (int rt = 0; rt < 2; ++rt) {
                    int r  = rt ? rB : rA;
                    int sr = rt ? sB : sA;
                    f4 v = acc[nt][rt];
                    float sh0 = eg0  * tanhf(v[0] + bias[0]);
                    float sc0 = 0.6f * tanhf(v[1] + bias[1]);
                    float sh1 = eg1  * tanhf(v[2] + bias[2]);
                    float sc1 = 0.6f * tanhf(v[3] + bias[3]);
                    int c = 32 + j0;                       // j0, j0+1 share an f4 block
                    int addr = r*64 + ((((c >> 2) ^ sr)) << 2) + (c & 3);
                    float z0  = zb[addr];
                    float z1v = zb[addr + 1];
                    zb[addr]     = fmaf(sc0, z0,  z0  + sh0);
                    zb[addr + 1] = fmaf(sc1, z1v, z1v + sh1);
                    float l01 = log1pf(sc0) + log1pf(sc1);
                    if (rt == 0) ldp0 += l01; else ldp1 += l01;
                }
            }
        }
        __syncthreads();

        // ---- reversal: z = z[:, ::-1] (logical f4-block pair swap) ----
        #pragma unroll
        for (int q = 0; q < 2; ++q) {
            int task = tid + q*256;          // 512 tasks = 64 rows x 8 left blocks
            int r = task >> 3, cfL = task & 7;
            int s = r & 7;
            float* pL = &zb[r*64 + ((cfL ^ s) << 2)];
            float* pR = &zb[r*64 + (((15 - cfL) ^ s) << 2)];
            f4 Lv = *(f4*)pL;
            f4 Rv = *(f4*)pR;
            f4 nL = { Rv[3], Rv[2], Rv[1], Rv[0] };
            f4 nR = { Lv[3], Lv[2], Lv[1], Lv[0] };
            *(f4*)pL = nL;
            *(f4*)pR = nR;
        }
    }
    __syncthreads();

    // ---- store z ----
    {
        f4* oz = (f4*)(out + (size_t)row0 * 64);
        #pragma unroll
        for (int q = 0; q < 4; ++q) {
            int idx4 = tid + q*256;
            int r = idx4 >> 4, cf = idx4 & 15;
            oz[idx4] = *(const f4*)&zb[r*64 + ((cf ^ (r & 7)) << 2)];
        }
    }

    // ---- logdet: reduce ldp over the 4 lane-groups, combine wc halves via hb scratch ----
    float v0 = ldp0 + __shfl_xor(ldp0, 16); v0 += __shfl_xor(v0, 32);
    float v1 = ldp1 + __shfl_xor(ldp1, 16); v1 += __shfl_xor(v1, 32);
    if (lg4 == 0) {
        hb[rA*2 + wc] = v0;
        hb[rB*2 + wc] = v1;
    }
    __syncthreads();
    if (tid < 64) {
        int gr = row0 + tid;
        out[(size_t)BB * 64 + gr] = logdet_in[gr] + lsum + hb[tid*2] + hb[tid*2 + 1];
    }
}

extern "C" void kernel_launch(void* const* d_in, const int* in_sizes, int n_in,
                              void* d_out, int out_size, void* d_ws, size_t ws_size,
                              hipStream_t stream)
{
    const float* x    = (const float*)d_in[0];
    const float* ld   = (const float*)d_in[1];
    const float* b    = (const float*)d_in[2];
    const float* logs = (const float*)d_in[3];
    const float* W1   = (const float*)d_in[4];
    const float* b1   = (const float*)d_in[5];
    const float* W2   = (const float*)d_in[6];
    const float* b2   = (const float*)d_in[7];
    const float* Wf   = (const float*)d_in[8];
    const float* bf   = (const float*)d_in[9];
    const float* lg   = (const float*)d_in[10];
    _Float16* wt = (_Float16*)d_ws;
    float* out = (float*)d_out;

    prep_weights<<<WTOT_F16 / 256, 256, 0, stream>>>(W1, W2, Wf, wt);
    flow_mfma<<<1024, 256, 0, stream>>>(x, ld, b, logs, b1, b2, bf, lg, wt, out);
}